// Round 1
// baseline (86920.251 us; speedup 1.0000x reference)
//
#include <hip/hip_runtime.h>
#include <hip/hip_cooperative_groups.h>

namespace cg = cooperative_groups;

constexpr int kB = 64;
constexpr int kT = 1024;
constexpr int kC = 128;
constexpr int kH = 512;

__device__ __forceinline__ float sigmoidf_(float v) {
    return 1.0f / (1.0f + __expf(-v));
}

// Persistent GRU kernel.
// Grid: 256 wgs x 256 threads. wg -> (bb in [0,4): 16 batches, jb in [0,64): 8 cols).
// Thread: s = tid>>7 (K-half), rr = tid&127 -> b_loc = rr>>3, j_loc = rr&7.
// s=0 covers h-k [0,320); s=1 covers h-k [320,512) + x-k [0,128)  (320 MACs each, balanced).
__global__ __launch_bounds__(256, 1)
void gru_seq_kernel(const float* __restrict__ x,
                    const float* __restrict__ h0,
                    const float* __restrict__ w_ih,
                    const float* __restrict__ w_hh,
                    const float* __restrict__ b_ih,
                    const float* __restrict__ b_hh,
                    float* __restrict__ hs_out,   // d_out, [B,T,H] (overwritten later by post)
                    float* __restrict__ h_final,  // d_out + B*T*H
                    float* __restrict__ h_ws)     // 2 * B*H floats (double buffer)
{
    cg::grid_group grid = cg::this_grid();

    const int wg  = blockIdx.x;          // 0..255
    const int bb  = wg >> 6;             // 0..3
    const int jb  = wg & 63;             // 0..63
    const int tid = threadIdx.x;
    const int s   = tid >> 7;            // K-half
    const int rr  = tid & 127;
    const int b   = bb * 16 + (rr >> 3);
    const int j   = jb * 8  + (rr & 7);

    __shared__ float4 red[128];

    // Weight row pointers (gate order per PyTorch/reference: r=[0,H), z=[H,2H), n=[2H,3H))
    const float4* whr = (const float4*)(w_hh + (size_t)j          * kH);
    const float4* whz = (const float4*)(w_hh + (size_t)(kH + j)   * kH);
    const float4* whn = (const float4*)(w_hh + (size_t)(2*kH + j) * kH);
    const float4* wir = (const float4*)(w_ih + (size_t)j          * kC);
    const float4* wiz = (const float4*)(w_ih + (size_t)(kH + j)   * kC);
    const float4* win = (const float4*)(w_ih + (size_t)(2*kH + j) * kC);

    // Biases, hoisted (only finisher threads use them)
    const float brz = b_ih[j]        + b_hh[j];
    const float bzz = b_ih[kH + j]   + b_hh[kH + j];
    const float bxn = b_ih[2*kH + j];
    const float bhn = b_hh[2*kH + j];

    // Init h state (each s==0 thread owns a unique (b,j) across the grid)
    if (s == 0) h_ws[b * kH + j] = h0[b * kH + j];
    __threadfence();
    grid.sync();

    const int k40 = s ? 80 : 0;    // float4 index range over h
    const int k41 = s ? 128 : 80;

    for (int t = 0; t < kT; ++t) {
        const float* h_cur = h_ws + (t & 1) * (kB * kH);
        float* h_nxt       = h_ws + ((t + 1) & 1) * (kB * kH);

        const float4* hv = (const float4*)(h_cur + b * kH);
        float ar = 0.f, az = 0.f, ahn = 0.f, axn = 0.f;

        for (int k4 = k40; k4 < k41; ++k4) {
            const float4 h4 = hv[k4];
            const float4 r4 = whr[k4];
            const float4 z4 = whz[k4];
            const float4 n4 = whn[k4];
            ar  += h4.x*r4.x + h4.y*r4.y + h4.z*r4.z + h4.w*r4.w;
            az  += h4.x*z4.x + h4.y*z4.y + h4.z*z4.z + h4.w*z4.w;
            ahn += h4.x*n4.x + h4.y*n4.y + h4.z*n4.z + h4.w*n4.w;
        }

        if (s) {
            const float4* xv = (const float4*)(x + ((size_t)b * kT + t) * kC);
            for (int k4 = 0; k4 < kC/4; ++k4) {
                const float4 x4 = xv[k4];
                const float4 r4 = wir[k4];
                const float4 z4 = wiz[k4];
                const float4 n4 = win[k4];
                ar  += x4.x*r4.x + x4.y*r4.y + x4.z*r4.z + x4.w*r4.w;
                az  += x4.x*z4.x + x4.y*z4.y + x4.z*z4.z + x4.w*z4.w;
                axn += x4.x*n4.x + x4.y*n4.y + x4.z*n4.z + x4.w*n4.w;
            }
            red[rr] = make_float4(ar, az, ahn, axn);
        }
        __syncthreads();

        if (!s) {
            const float4 p = red[rr];
            ar  += p.x;
            az  += p.y;
            ahn += p.z;
            axn += p.w;
            const float rg   = sigmoidf_(ar + brz);
            const float zg   = sigmoidf_(az + bzz);
            const float ng   = tanhf(axn + bxn + rg * (ahn + bhn));
            const float hold = h_cur[b * kH + j];
            const float hnew = (1.f - zg) * ng + zg * hold;
            h_nxt[b * kH + j] = hnew;
            hs_out[((size_t)b * kT + t) * kH + j] = hnew;
            if (t == kT - 1) h_final[b * kH + j] = hnew;
        }
        __threadfence();
        grid.sync();
    }
}

// In-place post projection: out[b,t,:] = relu(hs[b,t,:] @ w_post^T + b_post).
// Each wg owns 16 rows of the flattened [B*T, H] matrix; stages them in LDS,
// then overwrites the same rows. D == H == 512.
__global__ __launch_bounds__(256, 1)
void post_kernel(const float* __restrict__ w_post,
                 const float* __restrict__ b_post,
                 float* __restrict__ out)
{
    __shared__ float hbuf[16][kH];
    const int tid = threadIdx.x;
    const size_t row0 = (size_t)blockIdx.x * 16;

    const float4* src = (const float4*)(out + row0 * kH);
    float4* hb4 = (float4*)hbuf;
    for (int i = tid; i < 16 * kH / 4; i += 256) hb4[i] = src[i];
    __syncthreads();

    for (int pass = 0; pass < 2; ++pass) {
        const int d = tid + pass * 256;
        const float4* wrow = (const float4*)(w_post + (size_t)d * kH);
        float acc[16];
        #pragma unroll
        for (int m = 0; m < 16; ++m) acc[m] = 0.f;
        for (int k4 = 0; k4 < kH/4; ++k4) {
            const float4 w4 = wrow[k4];
            #pragma unroll
            for (int m = 0; m < 16; ++m) {
                const float4 h4 = *(const float4*)&hbuf[m][k4*4];
                acc[m] += h4.x*w4.x + h4.y*w4.y + h4.z*w4.z + h4.w*w4.w;
            }
        }
        const float bp = b_post[d];
        #pragma unroll
        for (int m = 0; m < 16; ++m) {
            out[(row0 + m) * kH + d] = fmaxf(acc[m] + bp, 0.f);
        }
    }
}

extern "C" void kernel_launch(void* const* d_in, const int* in_sizes, int n_in,
                              void* d_out, int out_size, void* d_ws, size_t ws_size,
                              hipStream_t stream) {
    const float* x      = (const float*)d_in[0];
    const float* h0     = (const float*)d_in[1];
    const float* w_ih   = (const float*)d_in[2];
    const float* w_hh   = (const float*)d_in[3];
    const float* b_ih   = (const float*)d_in[4];
    const float* b_hh   = (const float*)d_in[5];
    const float* w_post = (const float*)d_in[6];
    const float* b_post = (const float*)d_in[7];

    float* out     = (float*)d_out;
    float* h_final = out + (size_t)kB * kT * kH;
    float* h_ws    = (float*)d_ws;   // 2 * B*H floats = 256 KB

    void* args[] = { (void*)&x, (void*)&h0, (void*)&w_ih, (void*)&w_hh,
                     (void*)&b_ih, (void*)&b_hh, (void*)&out, (void*)&h_final,
                     (void*)&h_ws };
    hipLaunchCooperativeKernel((void*)gru_seq_kernel, dim3(256), dim3(256),
                               args, 0, stream);

    post_kernel<<<dim3(kB * kT / 16), dim3(256), 0, stream>>>(w_post, b_post, out);
}

// Round 2
// 16913.818 us; speedup vs baseline: 5.1390x; 5.1390x over previous
//
#include <hip/hip_runtime.h>

constexpr int kB = 64;
constexpr int kT = 1024;
constexpr int kC = 128;
constexpr int kH = 512;

#define SCOPE_AGENT __HIP_MEMORY_SCOPE_AGENT

__device__ __forceinline__ float sigmoidf_(float v) {
    return 1.0f / (1.0f + __expf(-v));
}

// Persistent GRU kernel, NO grid-wide sync.
// 256 wgs x 512 threads, 1 wg/CU (101KB LDS).
// Grid is split into 4 independent groups of 64 wgs; group g owns batches
// [g*16, g*16+16) and never communicates outside its group (GRU mixes only
// across H). Per-step sync = custom 64-wg sense-reversing barrier in d_ws.
// h state is exchanged via device-scope (cache-bypassing) atomics; weights
// are LDS-stationary for the whole kernel.
//
// Thread map: tid = s*128 + bl*8 + jl;  s in [0,4) = K-split,
// bl in [0,16) = batch within group, jl in [0,8) = column within j-block.
// wg = grp*64 + jb; thread's output column j = jb*8 + jl.
// Combined K space in float4 units: [0,128) = h (512 floats), [128,160) = x.
// s covers [s*40, s*40+40) -> 480 FMAs per gate-triple per thread per step.
__global__ __launch_bounds__(512, 1)
void gru_seq_kernel(const float* __restrict__ x,
                    const float* __restrict__ h0,
                    const float* __restrict__ w_ih,
                    const float* __restrict__ w_hh,
                    const float* __restrict__ b_ih,
                    const float* __restrict__ b_hh,
                    float* __restrict__ hs_out,   // d_out, [B,T,H]
                    float* __restrict__ h_final,  // d_out + B*T*H
                    unsigned* __restrict__ bar,   // d_ws: 4 groups x 64 uints
                    float* __restrict__ h_ws)     // d_ws+4KB: 2 x B*H floats
{
    const int wg  = blockIdx.x;
    const int grp = wg >> 6;          // batch group 0..3
    const int jb  = wg & 63;          // j-block 0..63
    const int tid = threadIdx.x;
    const int s   = tid >> 7;         // K-split 0..3
    const int rr  = tid & 127;
    const int bl  = rr >> 3;          // 0..15
    const int jl  = rr & 7;           // 0..7
    const int b   = grp * 16 + bl;
    const int j   = jb * 8 + jl;

    // +4 float pad per row: row stride 2064B -> 8 rows spread over all 32
    // banks (bank offset +4 per row) -> conflict-free b128 broadcast reads.
    __shared__ float  wh[3][8][kH + 4];   // 49.5 KB  w_hh rows for this j-block
    __shared__ float  wi[3][8][kC + 4];   // 12.7 KB  w_ih rows
    __shared__ float  hbuf[16][kH + 4];   // 33 KB    staged h rows (this group)
    __shared__ float4 red[3][128];        // 6 KB     K-split partials

    unsigned* cnt = bar + grp * 64;        // 256B per group
    unsigned* gen = bar + grp * 64 + 16;   // separate cacheline

    // ---- one-time weight staging into LDS ----
    for (int i = tid; i < 3 * 8 * (kH / 4); i += 512) {     // 3072 float4
        int g  = i >> 10;
        int rw = (i >> 7) & 7;
        int k4 = i & 127;
        *(float4*)&wh[g][rw][k4 * 4] =
            *(const float4*)&w_hh[((size_t)(g * kH + jb * 8 + rw)) * kH + k4 * 4];
    }
    for (int i = tid; i < 3 * 8 * (kC / 4); i += 512) {     // 768 float4
        int g  = i >> 8;
        int rw = (i >> 5) & 7;
        int k4 = i & 31;
        *(float4*)&wi[g][rw][k4 * 4] =
            *(const float4*)&w_ih[((size_t)(g * kH + jb * 8 + rw)) * kC + k4 * 4];
    }

    // biases (only s==0 finisher threads use them)
    const float brz = b_ih[j]          + b_hh[j];
    const float bzz = b_ih[kH + j]     + b_hh[kH + j];
    const float bxn = b_ih[2 * kH + j];
    const float bhn = b_hh[2 * kH + j];

    // ---- init h state (each s==0 thread owns a unique (b,j)) ----
    if (s == 0) {
        __hip_atomic_store(h_ws + (size_t)b * kH + j, h0[(size_t)b * kH + j],
                           __ATOMIC_RELAXED, SCOPE_AGENT);
    }

    // group barrier lambda
    auto group_barrier = [&]() {
        __syncthreads();   // all wg threads' stores drained (vmcnt 0)
        if (tid == 0) {
            unsigned g0 = __hip_atomic_load(gen, __ATOMIC_RELAXED, SCOPE_AGENT);
            unsigned old = __hip_atomic_fetch_add(cnt, 1u, __ATOMIC_ACQ_REL, SCOPE_AGENT);
            if (old == 63u) {
                __hip_atomic_store(cnt, 0u, __ATOMIC_RELAXED, SCOPE_AGENT);
                __hip_atomic_fetch_add(gen, 1u, __ATOMIC_RELEASE, SCOPE_AGENT);
            } else {
                while (__hip_atomic_load(gen, __ATOMIC_RELAXED, SCOPE_AGENT) == g0) {}
                (void)__hip_atomic_load(gen, __ATOMIC_ACQUIRE, SCOPE_AGENT);
            }
        }
        __syncthreads();
    };

    group_barrier();   // h0 visible group-wide

    for (int t = 0; t < kT; ++t) {
        const float* h_cur = h_ws + (t & 1) * (kB * kH);
        float*       h_nxt = h_ws + ((t + 1) & 1) * (kB * kH);

        // ---- stage this group's 16 h rows into LDS (coherent atomic loads) ----
        {
            const unsigned long long* hsrc =
                (const unsigned long long*)(h_cur + (size_t)grp * 16 * kH);
            for (int i = tid; i < 4096; i += 512) {     // 16 rows x 256 u64
                int rw = i >> 8;
                int kk = i & 255;
                unsigned long long v = __hip_atomic_load(
                    hsrc + (size_t)rw * (kH / 2) + kk, __ATOMIC_RELAXED, SCOPE_AGENT);
                *(unsigned long long*)&hbuf[rw][kk * 2] = v;
            }
        }
        __syncthreads();

        // ---- gate dots ----
        float ar = 0.f, az = 0.f, ahn = 0.f, axn = 0.f;
        {
            int k4     = s * 40;
            int k4_end = (s + 1) * 40;
            if (k4_end > 128) k4_end = 128;
            for (; k4 < k4_end; ++k4) {
                const float4 h4 = *(const float4*)&hbuf[bl][k4 * 4];
                const float4 r4 = *(const float4*)&wh[0][jl][k4 * 4];
                const float4 z4 = *(const float4*)&wh[1][jl][k4 * 4];
                const float4 n4 = *(const float4*)&wh[2][jl][k4 * 4];
                ar  += h4.x * r4.x + h4.y * r4.y + h4.z * r4.z + h4.w * r4.w;
                az  += h4.x * z4.x + h4.y * z4.y + h4.z * z4.z + h4.w * z4.w;
                ahn += h4.x * n4.x + h4.y * n4.y + h4.z * n4.z + h4.w * n4.w;
            }
        }
        if (s == 3) {
            const float4* xv = (const float4*)(x + ((size_t)b * kT + t) * kC);
            for (int q = 0; q < 32; ++q) {
                const float4 x4 = xv[q];
                const float4 r4 = *(const float4*)&wi[0][jl][q * 4];
                const float4 z4 = *(const float4*)&wi[1][jl][q * 4];
                const float4 n4 = *(const float4*)&wi[2][jl][q * 4];
                ar  += x4.x * r4.x + x4.y * r4.y + x4.z * r4.z + x4.w * r4.w;
                az  += x4.x * z4.x + x4.y * z4.y + x4.z * z4.z + x4.w * z4.w;
                axn += x4.x * n4.x + x4.y * n4.y + x4.z * n4.z + x4.w * n4.w;
            }
        }

        if (s) red[s - 1][rr] = make_float4(ar, az, ahn, axn);
        __syncthreads();

        if (s == 0) {
            const float4 p1 = red[0][rr];
            const float4 p2 = red[1][rr];
            const float4 p3 = red[2][rr];
            ar  += p1.x + p2.x + p3.x;
            az  += p1.y + p2.y + p3.y;
            ahn += p1.z + p2.z + p3.z;
            axn += p1.w + p2.w + p3.w;

            const float rg   = sigmoidf_(ar + brz);
            const float zg   = sigmoidf_(az + bzz);
            const float ng   = tanhf(axn + bxn + rg * (ahn + bhn));
            const float hold = hbuf[bl][j];
            const float hnew = (1.f - zg) * ng + zg * hold;

            __hip_atomic_store(h_nxt + (size_t)b * kH + j, hnew,
                               __ATOMIC_RELAXED, SCOPE_AGENT);
            hs_out[((size_t)b * kT + t) * kH + j] = hnew;
            if (t == kT - 1) h_final[(size_t)b * kH + j] = hnew;
        }

        group_barrier();
    }
}

// In-place post projection: out[b,t,:] = relu(hs[b,t,:] @ w_post^T + b_post).
__global__ __launch_bounds__(256, 1)
void post_kernel(const float* __restrict__ w_post,
                 const float* __restrict__ b_post,
                 float* __restrict__ out)
{
    __shared__ float hbuf[16][kH];
    const int tid = threadIdx.x;
    const size_t row0 = (size_t)blockIdx.x * 16;

    const float4* src = (const float4*)(out + row0 * kH);
    float4* hb4 = (float4*)hbuf;
    for (int i = tid; i < 16 * kH / 4; i += 256) hb4[i] = src[i];
    __syncthreads();

    for (int pass = 0; pass < 2; ++pass) {
        const int d = tid + pass * 256;
        const float4* wrow = (const float4*)(w_post + (size_t)d * kH);
        float acc[16];
        #pragma unroll
        for (int m = 0; m < 16; ++m) acc[m] = 0.f;
        for (int k4 = 0; k4 < kH / 4; ++k4) {
            const float4 w4 = wrow[k4];
            #pragma unroll
            for (int m = 0; m < 16; ++m) {
                const float4 h4 = *(const float4*)&hbuf[m][k4 * 4];
                acc[m] += h4.x * w4.x + h4.y * w4.y + h4.z * w4.z + h4.w * w4.w;
            }
        }
        const float bp = b_post[d];
        #pragma unroll
        for (int m = 0; m < 16; ++m) {
            out[(row0 + m) * kH + d] = fmaxf(acc[m] + bp, 0.f);
        }
    }
}

extern "C" void kernel_launch(void* const* d_in, const int* in_sizes, int n_in,
                              void* d_out, int out_size, void* d_ws, size_t ws_size,
                              hipStream_t stream) {
    const float* x      = (const float*)d_in[0];
    const float* h0     = (const float*)d_in[1];
    const float* w_ih   = (const float*)d_in[2];
    const float* w_hh   = (const float*)d_in[3];
    const float* b_ih   = (const float*)d_in[4];
    const float* b_hh   = (const float*)d_in[5];
    const float* w_post = (const float*)d_in[6];
    const float* b_post = (const float*)d_in[7];

    float* out     = (float*)d_out;
    float* h_final = out + (size_t)kB * kT * kH;

    unsigned* bar = (unsigned*)d_ws;                    // 1KB of barrier state
    float* h_ws   = (float*)((char*)d_ws + 4096);       // 2 x B*H floats

    // Barrier counters/generations must start at 0 every launch (d_ws is
    // poisoned 0xAA once and never re-poisoned between replays).
    hipMemsetAsync(d_ws, 0, 4096, stream);

    void* args[] = { (void*)&x, (void*)&h0, (void*)&w_ih, (void*)&w_hh,
                     (void*)&b_ih, (void*)&b_hh, (void*)&out, (void*)&h_final,
                     (void*)&bar, (void*)&h_ws };
    // Cooperative launch only to guarantee all 256 wgs are co-resident
    // (required for the custom barriers); cg::grid.sync() is NOT used.
    hipLaunchCooperativeKernel((void*)gru_seq_kernel, dim3(256), dim3(512),
                               args, 0, stream);

    post_kernel<<<dim3(kB * kT / 16), dim3(256), 0, stream>>>(w_post, b_post, out);
}

// Round 4
// 8693.592 us; speedup vs baseline: 9.9982x; 1.9456x over previous
//
#include <hip/hip_runtime.h>

constexpr int kB = 64;
constexpr int kT = 1024;
constexpr int kC = 128;
constexpr int kH = 512;

constexpr int kWgPerGrp = 32;   // wgs per group (16 cols each)
constexpr int kRows     = 8;    // batches per group
constexpr int kWStride  = 520;  // w_hh LDS row: 512 data + 8 pad floats
constexpr int kHStride  = 652;  // hbuf row: 512 h + 128 x + 12 pad floats

#define SCOPE_AGENT __HIP_MEMORY_SCOPE_AGENT

__device__ __forceinline__ float sigmoidf_(float v) {
    return 1.0f / (1.0f + __expf(-v));
}

// Persistent GRU. 256 wgs x 256 threads (4 waves), 1 wg/CU (118KB LDS).
// 8 independent groups of 32 wgs; group g owns batches [g*8, g*8+8).
// wg = grp*32 + jb owns output columns [jb*16, jb*16+16).
// w_hh slice LDS-stationary; w_ih slice preloaded into REGISTERS (12 float4
// per thread, t-invariant addresses). hbuf rows are [h(512) | x(128)].
// Thread map: tid = wave(2b) | jp_lo(1b) | bq(1b) | s(4b):
//   jp = tid>>5 (j-pair, t_j=2), bq (batch quad, t_b=4), s = K-slice.
// Strided K-split: thread s covers h-k4 = s + 16m, m in [0,8); x-k4 covered
// via registers at x-offset s*4 + mm*64, mm in [0,2). n-gate keeps separate
// h/x accumulators (reference: n = tanh(xn + r*hn)).
// Reduction over s: 4x shfl_xor butterfly (s = low 4 bits of lane id).
// Per-step sync: all-report flag barrier (store own flag, poll all 32).
__global__ __launch_bounds__(256, 1)
void gru_seq_kernel(const float* __restrict__ x,
                    const float* __restrict__ h0,
                    const float* __restrict__ w_ih,
                    const float* __restrict__ w_hh,
                    const float* __restrict__ b_ih,
                    const float* __restrict__ b_hh,
                    float* __restrict__ hs_out,   // d_out, [B,T,H]
                    float* __restrict__ h_final,  // d_out + B*T*H
                    unsigned* __restrict__ flags, // d_ws: 8 x 32 uints
                    float* __restrict__ h_ws)     // d_ws+4KB: 2 x B*H floats
{
    const int wg  = blockIdx.x;
    const int grp = wg >> 5;
    const int jb  = wg & 31;
    const int tid = threadIdx.x;
    const int jp  = tid >> 5;          // 0..7
    const int bq  = (tid >> 4) & 1;    // batch quad
    const int s   = tid & 15;          // K-slice (low 4 bits of lane)
    const int b0  = grp * kRows;

    __shared__ float wh[3][16][kWStride];    // 99,840 B  (w_hh rows, this j-block)
    __shared__ float hbuf[kRows][kHStride];  // 20,864 B  ([h | x] per batch row)

    // ---- one-time w_hh staging into LDS ----
    for (int idx = tid; idx < 3 * 16 * 128; idx += 256) {
        const int g   = idx >> 11;
        const int rem = idx & 2047;
        const int col = rem >> 7;
        const int k4  = rem & 127;
        *(float4*)&wh[g][col][k4 * 4] =
            *(const float4*)&w_hh[((size_t)(g * kH + jb * 16 + col)) * kH + k4 * 4];
    }

    // ---- one-time w_ih slice into registers: wiR[gate][jj][mm] ----
    float4 wiR[3][2][2];
    #pragma unroll
    for (int g = 0; g < 3; ++g)
        #pragma unroll
        for (int jj = 0; jj < 2; ++jj)
            #pragma unroll
            for (int mm = 0; mm < 2; ++mm)
                wiR[g][jj][mm] = *(const float4*)
                    &w_ih[((size_t)(g * kH + jb * 16 + jp * 2 + jj)) * kC
                          + s * 4 + mm * 64];

    // biases for this thread's finish output (valid for s<8; harmless else)
    const int jg_f = jb * 16 + jp * 2 + (s & 1);
    const float brz = b_ih[jg_f]          + b_hh[jg_f];
    const float bzz = b_ih[kH + jg_f]     + b_hh[kH + jg_f];
    const float bxn = b_ih[2 * kH + jg_f];
    const float bhn = b_hh[2 * kH + jg_f];

    // ---- init h state: this wg's 8 rows x 16 cols slice of buffer 0 ----
    if (tid < 128) {
        const int row = tid >> 4;
        const int c   = tid & 15;
        const int jg  = jb * 16 + c;
        __hip_atomic_store(h_ws + (size_t)(b0 + row) * kH + jg,
                           h0[(size_t)(b0 + row) * kH + jg],
                           __ATOMIC_RELAXED, SCOPE_AGENT);
    }

    unsigned* myflag = flags + grp * kWgPerGrp + jb;
    const unsigned* pollflag = flags + grp * kWgPerGrp + (tid & 31);

    // all-report barrier: store own epoch flag, poll all 32
    auto group_barrier = [&](unsigned e) {
        __syncthreads();   // vmcnt(0) drain: prior global stores MALL-visible
        if (tid < kWgPerGrp) {
            if (tid == 0)
                __hip_atomic_store(myflag, e, __ATOMIC_RELAXED, SCOPE_AGENT);
            unsigned v;
            do {
                v = __hip_atomic_load(pollflag, __ATOMIC_RELAXED, SCOPE_AGENT);
            } while (__any((int)(v < e)));
        }
        __syncthreads();
    };

    group_barrier(1u);   // h0 + staged weights visible

    for (int t = 0; t < kT; ++t) {
        const float* h_cur = h_ws + (t & 1) * (kB * kH);
        float*       h_nxt = h_ws + ((t + 1) & 1) * (kB * kH);

        // ---- stage h rows (coherent u64 loads), 8 per thread ----
        {
            const unsigned long long* hsrc =
                (const unsigned long long*)(h_cur + (size_t)b0 * kH);
            #pragma unroll
            for (int q = 0; q < 8; ++q) {
                const int idx = tid + q * 256;
                const int row = idx >> 8;
                const int kk  = idx & 255;
                unsigned long long v = __hip_atomic_load(
                    hsrc + (size_t)row * (kH / 2) + kk, __ATOMIC_RELAXED, SCOPE_AGENT);
                *(unsigned long long*)&hbuf[row][kk * 2] = v;
            }
        }
        if (t == 0) {   // steady-state x is prefetched at the end of prev iter
            const int row = tid >> 5;
            const int f4i = tid & 31;
            *(float4*)&hbuf[row][512 + f4i * 4] =
                *(const float4*)&x[((size_t)(b0 + row) * kT + 0) * kC + f4i * 4];
        }
        __syncthreads();

        // ---- gate dots: acc[{r,z,n_h,n_x}][4 b][2 j] ----
        float acc[4][4][2];
        #pragma unroll
        for (int g = 0; g < 4; ++g)
            #pragma unroll
            for (int i = 0; i < 4; ++i) {
                acc[g][i][0] = 0.f; acc[g][i][1] = 0.f;
            }

        const float* hbase = &hbuf[bq * 4][s * 4];
        const float* wbase = &wh[0][jp * 2][s * 4];

        #pragma unroll
        for (int m = 0; m < 8; ++m) {         // h-part: k4 = s + 16m
            const int off = m * 64;
            float4 h4[4];
            #pragma unroll
            for (int i = 0; i < 4; ++i)
                h4[i] = *(const float4*)(hbase + i * kHStride + off);
            #pragma unroll
            for (int g = 0; g < 3; ++g) {
                #pragma unroll
                for (int jj = 0; jj < 2; ++jj) {
                    const float4 w4 = *(const float4*)(wbase + (g * 16 + jj) * kWStride + off);
                    #pragma unroll
                    for (int i = 0; i < 4; ++i)
                        acc[g][i][jj] += h4[i].x * w4.x + h4[i].y * w4.y
                                       + h4[i].z * w4.z + h4[i].w * w4.w;
                }
            }
        }
        #pragma unroll
        for (int mm = 0; mm < 2; ++mm) {      // x-part (weights in registers)
            const int off = 512 + mm * 64;
            float4 x4v[4];
            #pragma unroll
            for (int i = 0; i < 4; ++i)
                x4v[i] = *(const float4*)(hbase + i * kHStride + off);
            #pragma unroll
            for (int g = 0; g < 3; ++g) {
                const int ga = (g == 2) ? 3 : g;   // x-side n goes to acc[3]
                #pragma unroll
                for (int jj = 0; jj < 2; ++jj) {
                    const float4 w4 = wiR[g][jj][mm];
                    #pragma unroll
                    for (int i = 0; i < 4; ++i)
                        acc[ga][i][jj] += x4v[i].x * w4.x + x4v[i].y * w4.y
                                        + x4v[i].z * w4.z + x4v[i].w * w4.w;
                }
            }
        }

        // ---- butterfly allreduce over s (lane-xor 1,2,4,8) ----
        #pragma unroll
        for (int g = 0; g < 4; ++g)
            #pragma unroll
            for (int i = 0; i < 4; ++i)
                #pragma unroll
                for (int jj = 0; jj < 2; ++jj) {
                    float v = acc[g][i][jj];
                    v += __shfl_xor(v, 1);
                    v += __shfl_xor(v, 2);
                    v += __shfl_xor(v, 4);
                    v += __shfl_xor(v, 8);
                    acc[g][i][jj] = v;
                }

        __syncthreads();   // all compute reads of hbuf x-section done

        // ---- prefetch x for step t+1 into hbuf x-section ----
        if (t + 1 < kT) {
            const int row = tid >> 5;
            const int f4i = tid & 31;
            *(float4*)&hbuf[row][512 + f4i * 4] =
                *(const float4*)&x[((size_t)(b0 + row) * kT + (t + 1)) * kC + f4i * 4];
        }

        // ---- finish: lane s<8 owns output (i = s>>1, jj = s&1) ----
        if (s < 8) {
            float ar, az, ahn, axn;
            switch (s) {
                case 0: ar=acc[0][0][0]; az=acc[1][0][0]; ahn=acc[2][0][0]; axn=acc[3][0][0]; break;
                case 1: ar=acc[0][0][1]; az=acc[1][0][1]; ahn=acc[2][0][1]; axn=acc[3][0][1]; break;
                case 2: ar=acc[0][1][0]; az=acc[1][1][0]; ahn=acc[2][1][0]; axn=acc[3][1][0]; break;
                case 3: ar=acc[0][1][1]; az=acc[1][1][1]; ahn=acc[2][1][1]; axn=acc[3][1][1]; break;
                case 4: ar=acc[0][2][0]; az=acc[1][2][0]; ahn=acc[2][2][0]; axn=acc[3][2][0]; break;
                case 5: ar=acc[0][2][1]; az=acc[1][2][1]; ahn=acc[2][2][1]; axn=acc[3][2][1]; break;
                case 6: ar=acc[0][3][0]; az=acc[1][3][0]; ahn=acc[2][3][0]; axn=acc[3][3][0]; break;
                default:ar=acc[0][3][1]; az=acc[1][3][1]; ahn=acc[2][3][1]; axn=acc[3][3][1]; break;
            }
            const int   bloc = bq * 4 + (s >> 1);
            const int   bg   = b0 + bloc;
            const float rg   = sigmoidf_(ar + brz);
            const float zg   = sigmoidf_(az + bzz);
            const float ng   = tanhf(axn + bxn + rg * (ahn + bhn));
            const float hold = hbuf[bloc][jg_f];
            const float hnew = (1.f - zg) * ng + zg * hold;

            __hip_atomic_store(h_nxt + (size_t)bg * kH + jg_f, hnew,
                               __ATOMIC_RELAXED, SCOPE_AGENT);
            hs_out[((size_t)bg * kT + t) * kH + jg_f] = hnew;
            if (t == kT - 1) h_final[(size_t)bg * kH + jg_f] = hnew;
        }

        group_barrier((unsigned)(t + 2));
    }
}

// In-place post projection: out[b,t,:] = relu(hs[b,t,:] @ w_post^T + b_post).
__global__ __launch_bounds__(256, 1)
void post_kernel(const float* __restrict__ w_post,
                 const float* __restrict__ b_post,
                 float* __restrict__ out)
{
    __shared__ float hbuf[16][kH];
    const int tid = threadIdx.x;
    const size_t row0 = (size_t)blockIdx.x * 16;

    const float4* src = (const float4*)(out + row0 * kH);
    float4* hb4 = (float4*)hbuf;
    for (int i = tid; i < 16 * kH / 4; i += 256) hb4[i] = src[i];
    __syncthreads();

    for (int pass = 0; pass < 2; ++pass) {
        const int d = tid + pass * 256;
        const float4* wrow = (const float4*)(w_post + (size_t)d * kH);
        float acc[16];
        #pragma unroll
        for (int m = 0; m < 16; ++m) acc[m] = 0.f;
        for (int k4 = 0; k4 < kH / 4; ++k4) {
            const float4 w4 = wrow[k4];
            #pragma unroll
            for (int m = 0; m < 16; ++m) {
                const float4 h4 = *(const float4*)&hbuf[m][k4 * 4];
                acc[m] += h4.x * w4.x + h4.y * w4.y + h4.z * w4.z + h4.w * w4.w;
            }
        }
        const float bp = b_post[d];
        #pragma unroll
        for (int m = 0; m < 16; ++m) {
            out[(row0 + m) * kH + d] = fmaxf(acc[m] + bp, 0.f);
        }
    }
}

extern "C" void kernel_launch(void* const* d_in, const int* in_sizes, int n_in,
                              void* d_out, int out_size, void* d_ws, size_t ws_size,
                              hipStream_t stream) {
    const float* x      = (const float*)d_in[0];
    const float* h0     = (const float*)d_in[1];
    const float* w_ih   = (const float*)d_in[2];
    const float* w_hh   = (const float*)d_in[3];
    const float* b_ih   = (const float*)d_in[4];
    const float* b_hh   = (const float*)d_in[5];
    const float* w_post = (const float*)d_in[6];
    const float* b_post = (const float*)d_in[7];

    float* out     = (float*)d_out;
    float* h_final = out + (size_t)kB * kT * kH;

    unsigned* flags = (unsigned*)d_ws;              // 8 x 32 uints
    float* h_ws     = (float*)((char*)d_ws + 4096); // 2 x B*H floats

    // flags must start at 0 every launch (d_ws is not re-poisoned per replay)
    hipMemsetAsync(d_ws, 0, 4096, stream);

    void* args[] = { (void*)&x, (void*)&h0, (void*)&w_ih, (void*)&w_hh,
                     (void*)&b_ih, (void*)&b_hh, (void*)&out, (void*)&h_final,
                     (void*)&flags, (void*)&h_ws };
    // Cooperative launch for guaranteed co-residency; if the runtime refuses
    // (round-3 suspect: silent launch failure), fall back to a plain launch —
    // 256 wgs at 1 wg/CU on 256 CUs is co-resident in practice.
    hipError_t err = hipLaunchCooperativeKernel((void*)gru_seq_kernel,
                                                dim3(256), dim3(256),
                                                args, 0, stream);
    if (err != hipSuccess) {
        gru_seq_kernel<<<dim3(256), dim3(256), 0, stream>>>(
            x, h0, w_ih, w_hh, b_ih, b_hh, out, h_final, flags, h_ws);
    }

    post_kernel<<<dim3(kB * kT / 16), dim3(256), 0, stream>>>(w_post, b_post, out);
}

// Round 5
// 7118.611 us; speedup vs baseline: 12.2103x; 1.2212x over previous
//
#include <hip/hip_runtime.h>

constexpr int kB = 64;
constexpr int kT = 1024;
constexpr int kC = 128;
constexpr int kH = 512;

constexpr int kWgPerGrp = 32;   // wgs per group (16 cols each)
constexpr int kRows     = 8;    // batches per group
constexpr int kWStride  = 520;  // w_hh LDS row: 512 data + 8 pad floats
constexpr int kHStride  = 652;  // hbuf row: 512 h + 128 x + 12 pad floats

#define SCOPE_AGENT __HIP_MEMORY_SCOPE_AGENT

__device__ __forceinline__ float sigmoidf_(float v) {
    return 1.0f / (1.0f + __expf(-v));
}

// Persistent GRU. 256 wgs x 256 threads (4 waves), 1 wg/CU (118KB LDS).
// 8 independent groups of 32 wgs; grp = wg & 7 (XCD-clustered under the
// round-robin block->XCD heuristic; correctness does not depend on it).
// Group g owns batches [g*8, g*8+8); wg owns output columns [jb*16,+16).
// h-exchange goes THROUGH hs_out: step t's finish does one relaxed
// agent-scope atomic store (straight to MALL); step t+1 stages
// hs_out[:, t, :] with PLAIN coalesced float4 loads — addresses are fresh
// every step, so no reader cache can hold a stale copy (no fences needed).
// Ordering: atomic store -> __syncthreads (vmcnt drain) -> flag store;
// reader: poll flag -> plain load (miss -> L2/MALL, fresh).
// w_hh slice LDS-stationary; w_ih slice in registers. hbuf = [h(512)|x(128)].
// Thread map: tid = jp(3b) | bq(1b) | s(4b); strided K-split k4 = s + 16m.
// Reduction over s: 4x shfl_xor butterfly. Per-step sync: all-report flag
// barrier (store own flag, poll all 32).
__global__ __launch_bounds__(256, 1)
void gru_seq_kernel(const float* __restrict__ x,
                    const float* __restrict__ h0,
                    const float* __restrict__ w_ih,
                    const float* __restrict__ w_hh,
                    const float* __restrict__ b_ih,
                    const float* __restrict__ b_hh,
                    float* __restrict__ hs_out,   // d_out, [B,T,H]; also h-exchange
                    float* __restrict__ h_final,  // d_out + B*T*H
                    unsigned* __restrict__ flags) // d_ws: 8 x 32 uints
{
    const int wg  = blockIdx.x;
    const int grp = wg & 7;            // XCD-clustered group
    const int jb  = wg >> 3;           // 0..31
    const int tid = threadIdx.x;
    const int jp  = tid >> 5;          // 0..7
    const int bq  = (tid >> 4) & 1;    // batch quad
    const int s   = tid & 15;          // K-slice (low 4 bits of lane)
    const int b0  = grp * kRows;

    __shared__ float wh[3][16][kWStride];    // 99,840 B  (w_hh rows, this j-block)
    __shared__ float hbuf[kRows][kHStride];  // 20,864 B  ([h | x] per batch row)

    // ---- one-time w_hh staging into LDS ----
    for (int idx = tid; idx < 3 * 16 * 128; idx += 256) {
        const int g   = idx >> 11;
        const int rem = idx & 2047;
        const int col = rem >> 7;
        const int k4  = rem & 127;
        *(float4*)&wh[g][col][k4 * 4] =
            *(const float4*)&w_hh[((size_t)(g * kH + jb * 16 + col)) * kH + k4 * 4];
    }

    // ---- one-time w_ih slice into registers: wiR[gate][jj][mm] ----
    float4 wiR[3][2][2];
    #pragma unroll
    for (int g = 0; g < 3; ++g)
        #pragma unroll
        for (int jj = 0; jj < 2; ++jj)
            #pragma unroll
            for (int mm = 0; mm < 2; ++mm)
                wiR[g][jj][mm] = *(const float4*)
                    &w_ih[((size_t)(g * kH + jb * 16 + jp * 2 + jj)) * kC
                          + s * 4 + mm * 64];

    // biases for this thread's finish output (valid for s<8; harmless else)
    const int jg_f = jb * 16 + jp * 2 + (s & 1);
    const float brz = b_ih[jg_f]          + b_hh[jg_f];
    const float bzz = b_ih[kH + jg_f]     + b_hh[kH + jg_f];
    const float bxn = b_ih[2 * kH + jg_f];
    const float bhn = b_hh[2 * kH + jg_f];

    unsigned* myflag = flags + grp * kWgPerGrp + jb;
    const unsigned* pollflag = flags + grp * kWgPerGrp + (tid & 31);

    // all-report barrier: store own epoch flag, poll all 32
    auto group_barrier = [&](unsigned e) {
        __syncthreads();   // vmcnt(0) drain: prior (atomic) stores MALL-visible
        if (tid < kWgPerGrp) {
            if (tid == 0)
                __hip_atomic_store(myflag, e, __ATOMIC_RELAXED, SCOPE_AGENT);
            unsigned v;
            do {
                v = __hip_atomic_load(pollflag, __ATOMIC_RELAXED, SCOPE_AGENT);
            } while (__any((int)(v < e)));
        }
        __syncthreads();
    };

    for (int t = 0; t < kT; ++t) {
        // ---- stage h rows: PLAIN float4 loads, 4 per thread ----
        // t==0: from h0. t>0: from hs_out[:, t-1, :] — fresh addresses every
        // step, so no cache staleness is possible.
        {
            #pragma unroll
            for (int q = 0; q < 4; ++q) {
                const int idx = tid + q * 256;     // 0..1023
                const int row = idx >> 7;          // 0..7
                const int f4  = idx & 127;
                float4 v;
                if (t == 0)
                    v = *(const float4*)&h0[(size_t)(b0 + row) * kH + f4 * 4];
                else
                    v = *(const float4*)
                        &hs_out[((size_t)(b0 + row) * kT + (t - 1)) * kH + f4 * 4];
                *(float4*)&hbuf[row][f4 * 4] = v;
            }
        }
        if (t == 0) {   // steady-state x is prefetched at the end of prev iter
            const int row = tid >> 5;
            const int f4i = tid & 31;
            *(float4*)&hbuf[row][512 + f4i * 4] =
                *(const float4*)&x[((size_t)(b0 + row) * kT + 0) * kC + f4i * 4];
        }
        __syncthreads();

        // ---- gate dots: acc[{r,z,n_h,n_x}][4 b][2 j] ----
        float acc[4][4][2];
        #pragma unroll
        for (int g = 0; g < 4; ++g)
            #pragma unroll
            for (int i = 0; i < 4; ++i) {
                acc[g][i][0] = 0.f; acc[g][i][1] = 0.f;
            }

        const float* hbase = &hbuf[bq * 4][s * 4];
        const float* wbase = &wh[0][jp * 2][s * 4];

        #pragma unroll
        for (int m = 0; m < 8; ++m) {         // h-part: k4 = s + 16m
            const int off = m * 64;
            float4 h4[4];
            #pragma unroll
            for (int i = 0; i < 4; ++i)
                h4[i] = *(const float4*)(hbase + i * kHStride + off);
            #pragma unroll
            for (int g = 0; g < 3; ++g) {
                #pragma unroll
                for (int jj = 0; jj < 2; ++jj) {
                    const float4 w4 = *(const float4*)(wbase + (g * 16 + jj) * kWStride + off);
                    #pragma unroll
                    for (int i = 0; i < 4; ++i)
                        acc[g][i][jj] += h4[i].x * w4.x + h4[i].y * w4.y
                                       + h4[i].z * w4.z + h4[i].w * w4.w;
                }
            }
        }
        #pragma unroll
        for (int mm = 0; mm < 2; ++mm) {      // x-part (weights in registers)
            const int off = 512 + mm * 64;
            float4 x4v[4];
            #pragma unroll
            for (int i = 0; i < 4; ++i)
                x4v[i] = *(const float4*)(hbase + i * kHStride + off);
            #pragma unroll
            for (int g = 0; g < 3; ++g) {
                const int ga = (g == 2) ? 3 : g;   // x-side n goes to acc[3]
                #pragma unroll
                for (int jj = 0; jj < 2; ++jj) {
                    const float4 w4 = wiR[g][jj][mm];
                    #pragma unroll
                    for (int i = 0; i < 4; ++i)
                        acc[ga][i][jj] += x4v[i].x * w4.x + x4v[i].y * w4.y
                                        + x4v[i].z * w4.z + x4v[i].w * w4.w;
                }
            }
        }

        // ---- butterfly allreduce over s (lane-xor 1,2,4,8) ----
        #pragma unroll
        for (int g = 0; g < 4; ++g)
            #pragma unroll
            for (int i = 0; i < 4; ++i)
                #pragma unroll
                for (int jj = 0; jj < 2; ++jj) {
                    float v = acc[g][i][jj];
                    v += __shfl_xor(v, 1);
                    v += __shfl_xor(v, 2);
                    v += __shfl_xor(v, 4);
                    v += __shfl_xor(v, 8);
                    acc[g][i][jj] = v;
                }

        __syncthreads();   // all compute reads of hbuf x-section done

        // ---- prefetch x for step t+1 into hbuf x-section ----
        if (t + 1 < kT) {
            const int row = tid >> 5;
            const int f4i = tid & 31;
            *(float4*)&hbuf[row][512 + f4i * 4] =
                *(const float4*)&x[((size_t)(b0 + row) * kT + (t + 1)) * kC + f4i * 4];
        }

        // ---- finish: lane s<8 owns output (i = s>>1, jj = s&1) ----
        if (s < 8) {
            float ar, az, ahn, axn;
            switch (s) {
                case 0: ar=acc[0][0][0]; az=acc[1][0][0]; ahn=acc[2][0][0]; axn=acc[3][0][0]; break;
                case 1: ar=acc[0][0][1]; az=acc[1][0][1]; ahn=acc[2][0][1]; axn=acc[3][0][1]; break;
                case 2: ar=acc[0][1][0]; az=acc[1][1][0]; ahn=acc[2][1][0]; axn=acc[3][1][0]; break;
                case 3: ar=acc[0][1][1]; az=acc[1][1][1]; ahn=acc[2][1][1]; axn=acc[3][1][1]; break;
                case 4: ar=acc[0][2][0]; az=acc[1][2][0]; ahn=acc[2][2][0]; axn=acc[3][2][0]; break;
                case 5: ar=acc[0][2][1]; az=acc[1][2][1]; ahn=acc[2][2][1]; axn=acc[3][2][1]; break;
                case 6: ar=acc[0][3][0]; az=acc[1][3][0]; ahn=acc[2][3][0]; axn=acc[3][3][0]; break;
                default:ar=acc[0][3][1]; az=acc[1][3][1]; ahn=acc[2][3][1]; axn=acc[3][3][1]; break;
            }
            const int   bloc = bq * 4 + (s >> 1);
            const int   bg   = b0 + bloc;
            const float rg   = sigmoidf_(ar + brz);
            const float zg   = sigmoidf_(az + bzz);
            const float ng   = tanhf(axn + bxn + rg * (ahn + bhn));
            const float hold = hbuf[bloc][jg_f];
            const float hnew = (1.f - zg) * ng + zg * hold;

            // single h-publish: atomic (MALL-visible) store into hs_out
            __hip_atomic_store(&hs_out[((size_t)bg * kT + t) * kH + jg_f], hnew,
                               __ATOMIC_RELAXED, SCOPE_AGENT);
            if (t == kT - 1) h_final[(size_t)bg * kH + jg_f] = hnew;
        }

        group_barrier((unsigned)(t + 1));
    }
}

// In-place post projection: out[b,t,:] = relu(hs[b,t,:] @ w_post^T + b_post).
__global__ __launch_bounds__(256, 1)
void post_kernel(const float* __restrict__ w_post,
                 const float* __restrict__ b_post,
                 float* __restrict__ out)
{
    __shared__ float hbuf[16][kH];
    const int tid = threadIdx.x;
    const size_t row0 = (size_t)blockIdx.x * 16;

    const float4* src = (const float4*)(out + row0 * kH);
    float4* hb4 = (float4*)hbuf;
    for (int i = tid; i < 16 * kH / 4; i += 256) hb4[i] = src[i];
    __syncthreads();

    for (int pass = 0; pass < 2; ++pass) {
        const int d = tid + pass * 256;
        const float4* wrow = (const float4*)(w_post + (size_t)d * kH);
        float acc[16];
        #pragma unroll
        for (int m = 0; m < 16; ++m) acc[m] = 0.f;
        for (int k4 = 0; k4 < kH / 4; ++k4) {
            const float4 w4 = wrow[k4];
            #pragma unroll
            for (int m = 0; m < 16; ++m) {
                const float4 h4 = *(const float4*)&hbuf[m][k4 * 4];
                acc[m] += h4.x * w4.x + h4.y * w4.y + h4.z * w4.z + h4.w * w4.w;
            }
        }
        const float bp = b_post[d];
        #pragma unroll
        for (int m = 0; m < 16; ++m) {
            out[(row0 + m) * kH + d] = fmaxf(acc[m] + bp, 0.f);
        }
    }
}

extern "C" void kernel_launch(void* const* d_in, const int* in_sizes, int n_in,
                              void* d_out, int out_size, void* d_ws, size_t ws_size,
                              hipStream_t stream) {
    const float* x      = (const float*)d_in[0];
    const float* h0     = (const float*)d_in[1];
    const float* w_ih   = (const float*)d_in[2];
    const float* w_hh   = (const float*)d_in[3];
    const float* b_ih   = (const float*)d_in[4];
    const float* b_hh   = (const float*)d_in[5];
    const float* w_post = (const float*)d_in[6];
    const float* b_post = (const float*)d_in[7];

    float* out     = (float*)d_out;
    float* h_final = out + (size_t)kB * kT * kH;

    unsigned* flags = (unsigned*)d_ws;   // 8 x 32 uints

    // flags must start at 0 every launch (d_ws is not re-poisoned per replay)
    hipMemsetAsync(d_ws, 0, 4096, stream);

    void* args[] = { (void*)&x, (void*)&h0, (void*)&w_ih, (void*)&w_hh,
                     (void*)&b_ih, (void*)&b_hh, (void*)&out, (void*)&h_final,
                     (void*)&flags };
    // Cooperative launch for guaranteed co-residency; fall back to a plain
    // launch if refused (256 wgs at 1 wg/CU on 256 CUs is co-resident).
    hipError_t err = hipLaunchCooperativeKernel((void*)gru_seq_kernel,
                                                dim3(256), dim3(256),
                                                args, 0, stream);
    if (err != hipSuccess) {
        gru_seq_kernel<<<dim3(256), dim3(256), 0, stream>>>(
            x, h0, w_ih, w_hh, b_ih, b_hh, out, h_final, flags);
    }

    post_kernel<<<dim3(kB * kT / 16), dim3(256), 0, stream>>>(w_post, b_post, out);
}